// Round 9
// baseline (369.566 us; speedup 1.0000x reference)
//
#include <hip/hip_runtime.h>
#include <hip/hip_fp16.h>

#define B_ 4
#define S_ 2048
#define H_ 1024
#define M_ (B_ * S_)  // 8192 flattened rows of x / q / k / v

typedef _Float16 f16;
typedef _Float16 f16x8 __attribute__((ext_vector_type(8)));
typedef _Float16 f16x4 __attribute__((ext_vector_type(4)));
typedef float f32x4 __attribute__((ext_vector_type(4)));

typedef __attribute__((address_space(3))) unsigned int* lds_u32p;
typedef const __attribute__((address_space(1))) unsigned int* gbl_u32p;

// async global->LDS, 16B per lane; LDS dest is wave-uniform base + lane*16
__device__ __forceinline__ void stage16(const f16* g, f16* l) {
  __builtin_amdgcn_global_load_lds((gbl_u32p)g, (lds_u32p)l, 16, 0, 0);
}

// ---------------------------------------------------------------------------
// One launch: x (8192 blocks) then Wq/Wk/Wv (1024 blocks each) -> fp16 RNE.
__global__ __launch_bounds__(256) void downconvert_all(
    const float* __restrict__ x, const float* __restrict__ W0,
    const float* __restrict__ W1, const float* __restrict__ W2,
    f16* __restrict__ xh, f16* __restrict__ Wh) {
  const int b = blockIdx.x;
  const float* src;
  f16* dst;
  long i;
  if (b < M_ * H_ / 1024) {  // 8192 x-blocks
    src = x; dst = xh;
    i = (long)b * 256 + threadIdx.x;
  } else {
    const int wb = b - M_ * H_ / 1024;
    const int sel = wb >> 10;               // 1024 blocks per W
    src = sel == 0 ? W0 : (sel == 1 ? W1 : W2);
    dst = Wh + (long)sel * H_ * H_;
    i = (long)(wb & 1023) * 256 + threadIdx.x;
  }
  f32x4 v = ((const f32x4*)src)[i];
  f16x4 h;
#pragma unroll
  for (int c = 0; c < 4; c++) h[c] = (f16)v[c];
  ((f16x4*)dst)[i] = h;
}

// ---------------------------------------------------------------------------
// Fused QKV projection — round-0 structure VERBATIM, NO swizzle
// (A/B r0/r6/r7/r8: swizzle costs ~8us here; conflicts are hidden).
__global__ __launch_bounds__(256, 2)
void qkv_gemm(const f16* __restrict__ xh, const f16* __restrict__ Wh,
              const float* __restrict__ bq, const float* __restrict__ bk,
              const float* __restrict__ bv, f16* __restrict__ qkv,
              f16* __restrict__ vT) {
  __shared__ __align__(16) f16 As[2 * 128 * 32];  // [chunk0 | chunk1]
  __shared__ __align__(16) f16 Bs[2 * 128 * 32];
  const int t = threadIdx.x;
  const int wave = t >> 6, lane = t & 63;
  const int quad = lane >> 4, l16 = lane & 15;
  const int wm = (wave & 1) * 64, wn = (wave >> 1) * 64;
  const int sel = blockIdx.y >> 3;             // 0=q 1=k 2=v
  const int ntile = (blockIdx.y & 7) * 128;
  const int mtile = blockIdx.x * 128;

  const f16* Ab = xh + (long)mtile * H_;
  const f16* Bb = Wh + (long)sel * H_ * H_ + (long)ntile * H_;

  const int r0 = t >> 2;        // staging row 0..63
  const int c8 = (t & 3) * 8;   // staging col (halfs)

  f32x4 acc[4][4] = {};

  for (int k0 = 0; k0 < H_; k0 += 64) {
    __syncthreads();
    stage16(Ab + (long)r0 * H_ + k0 + c8,             As + t * 8);
    stage16(Ab + (long)(r0 + 64) * H_ + k0 + c8,      As + 2048 + t * 8);
    stage16(Ab + (long)r0 * H_ + k0 + 32 + c8,        As + 4096 + t * 8);
    stage16(Ab + (long)(r0 + 64) * H_ + k0 + 32 + c8, As + 6144 + t * 8);
    stage16(Bb + (long)r0 * H_ + k0 + c8,             Bs + t * 8);
    stage16(Bb + (long)(r0 + 64) * H_ + k0 + c8,      Bs + 2048 + t * 8);
    stage16(Bb + (long)r0 * H_ + k0 + 32 + c8,        Bs + 4096 + t * 8);
    stage16(Bb + (long)(r0 + 64) * H_ + k0 + 32 + c8, Bs + 6144 + t * 8);
    __syncthreads();
#pragma unroll
    for (int kk = 0; kk < 2; kk++) {
      f16x8 ah[4], bh[4];
#pragma unroll
      for (int i = 0; i < 4; i++) {
        ah[i] = *(const f16x8*)&As[kk * 4096 + (wm + i * 16 + l16) * 32 + quad * 8];
        bh[i] = *(const f16x8*)&Bs[kk * 4096 + (wn + i * 16 + l16) * 32 + quad * 8];
      }
#pragma unroll
      for (int i = 0; i < 4; i++)
#pragma unroll
        for (int j = 0; j < 4; j++)
          acc[i][j] = __builtin_amdgcn_mfma_f32_16x16x32_f16(ah[i], bh[j], acc[i][j], 0, 0, 0);
    }
  }

  const float* bias = sel == 0 ? bq : (sel == 1 ? bk : bv);
  if (sel == 2) {
    // V transposed: vT[(b*H + n)*S + t_pos], b = m>>11, t_pos = m&2047.
#pragma unroll
    for (int j = 0; j < 4; j++) {
      int n = ntile + wn + j * 16 + l16;
      float bb = bias[n];
#pragma unroll
      for (int i = 0; i < 4; i++) {
        int m = mtile + wm + i * 16 + quad * 4;
        f16x4 pack;
#pragma unroll
        for (int r = 0; r < 4; r++) pack[r] = (f16)(acc[i][j][r] + bb);
        *(f16x4*)&vT[((long)(m >> 11) * H_ + n) * S_ + (m & 2047)] = pack;
      }
    }
  } else {
    f16* out = qkv + (long)sel * M_ * H_;
#pragma unroll
    for (int j = 0; j < 4; j++) {
      int n = ntile + wn + j * 16 + l16;
      float bb = bias[n];
#pragma unroll
      for (int i = 0; i < 4; i++) {
        int m = mtile + wm + i * 16 + quad * 4;
#pragma unroll
        for (int r = 0; r < 4; r++)
          out[(long)(m + r) * H_ + n] = (f16)(acc[i][j][r] + bb);
      }
    }
  }
}

// ---------------------------------------------------------------------------
// Scores GEMM: round-0 structure + chunk-XOR swizzle (r8 vs r7: ~-5us).
// C[z][m][n] = f16( sum_k A[z][m][k]*B[z][n][k] * alpha )
__global__ __launch_bounds__(256, 2)
void score_gemm(const f16* __restrict__ A, const f16* __restrict__ Bm,
                f16* __restrict__ C, float alpha) {
  __shared__ __align__(16) f16 As[2 * 128 * 32];
  __shared__ __align__(16) f16 Bs[2 * 128 * 32];
  const int t = threadIdx.x;
  const int wave = t >> 6, lane = t & 63;
  const int quad = lane >> 4, l16 = lane & 15;
  const int wm = (wave & 1) * 64, wn = (wave >> 1) * 64;
  const f16* Ab = A + (long)blockIdx.z * S_ * H_ + (long)blockIdx.x * 128 * H_;
  const f16* Bb = Bm + (long)blockIdx.z * S_ * H_ + (long)blockIdx.y * 128 * H_;
  const int r0 = t >> 2;
  const int c8 = ((t & 3) ^ ((r0 >> 1) & 3)) * 8;    // pre-swizzled source
  const int swz8 = (quad ^ ((l16 >> 1) & 3)) * 8;    // swizzled ds_read
  f32x4 acc[4][4] = {};
  for (int k0 = 0; k0 < H_; k0 += 64) {
    __syncthreads();
    stage16(Ab + (long)r0 * H_ + k0 + c8,             As + t * 8);
    stage16(Ab + (long)(r0 + 64) * H_ + k0 + c8,      As + 2048 + t * 8);
    stage16(Ab + (long)r0 * H_ + k0 + 32 + c8,        As + 4096 + t * 8);
    stage16(Ab + (long)(r0 + 64) * H_ + k0 + 32 + c8, As + 6144 + t * 8);
    stage16(Bb + (long)r0 * H_ + k0 + c8,             Bs + t * 8);
    stage16(Bb + (long)(r0 + 64) * H_ + k0 + c8,      Bs + 2048 + t * 8);
    stage16(Bb + (long)r0 * H_ + k0 + 32 + c8,        Bs + 4096 + t * 8);
    stage16(Bb + (long)(r0 + 64) * H_ + k0 + 32 + c8, Bs + 6144 + t * 8);
    __syncthreads();
#pragma unroll
    for (int kk = 0; kk < 2; kk++) {
      f16x8 af[4], bf[4];
#pragma unroll
      for (int i = 0; i < 4; i++) {
        af[i] = *(const f16x8*)&As[kk * 4096 + (wm + i * 16 + l16) * 32 + swz8];
        bf[i] = *(const f16x8*)&Bs[kk * 4096 + (wn + i * 16 + l16) * 32 + swz8];
      }
#pragma unroll
      for (int i = 0; i < 4; i++)
#pragma unroll
        for (int j = 0; j < 4; j++)
          acc[i][j] = __builtin_amdgcn_mfma_f32_16x16x32_f16(af[i], bf[j], acc[i][j], 0, 0, 0);
    }
  }
  f16* Cz = C + (long)blockIdx.z * S_ * S_;
  const long mb = (long)blockIdx.x * 128 + wm;
  const long nb = (long)blockIdx.y * 128 + wn;
#pragma unroll
  for (int i = 0; i < 4; i++)
#pragma unroll
    for (int j = 0; j < 4; j++) {
      long m = mb + i * 16 + quad * 4;
      long n = nb + j * 16 + l16;
#pragma unroll
      for (int r = 0; r < 4; r++)
        Cz[(m + r) * S_ + n] = (f16)(acc[i][j][r] * alpha);
    }
}

// ---------------------------------------------------------------------------
// PV GEMM with FUSED SOFTMAX (replaces softmax kernel + attn round-trip).
// A = raw quantized scores sc[z] (f16); per block, a stats prologue over its
// 128 rows computes c_r = -max_r*log2e - log2(sum_r exp(s-max_r)); the main
// loop transforms each A fragment in registers:
//   p = f16( exp2( s*log2e + c_r ) ) == f16( exp(s-m)/sum )   (same math as
// the old softmax_w, different f32 association; f16 RNE cast identical).
// Transform adds ~256 VALU cyc/K-tile, hidden in the stage-wait (VALUBusy
// was only ~18%). Stats are 8x redundant across y-blocks (~3us, L2-hot).
// out[z][m][n] = sum_k p[z][m][k] * vT[z][n][k]  (f32, straight to d_out)
__global__ __launch_bounds__(256, 2)
void pv_gemm(const f16* __restrict__ sc, const f16* __restrict__ vT,
             float* __restrict__ out) {
  __shared__ __align__(16) f16 As[2 * 128 * 32];
  __shared__ __align__(16) f16 Bs[2 * 128 * 32];
  __shared__ float rowc[128];
  const int t = threadIdx.x;
  const int wave = t >> 6, lane = t & 63;
  const int quad = lane >> 4, l16 = lane & 15;
  const int wm = (wave & 1) * 64, wn = (wave >> 1) * 64;
  const int mtile = blockIdx.x * 128, ntile = blockIdx.y * 128;
  const f16* Ab = sc + (long)blockIdx.z * S_ * S_ + (long)mtile * S_;
  const f16* Bb = vT + (long)blockIdx.z * H_ * S_ + (long)ntile * S_;

  // ---- softmax stats: thread t -> row t>>1, column half t&1 (1024 elems) --
  {
    const f16* rp = Ab + (long)(t >> 1) * S_ + (t & 1) * 1024;
    float mx = -3.0e38f;
#pragma unroll 4
    for (int i = 0; i < 128; ++i) {
      f16x8 v = ((const f16x8*)rp)[i];
#pragma unroll
      for (int c = 0; c < 8; ++c) mx = fmaxf(mx, (float)v[c]);
    }
    mx = fmaxf(mx, __shfl_xor(mx, 1));      // combine the two halves
    float s = 0.f;
#pragma unroll 4
    for (int i = 0; i < 128; ++i) {
      f16x8 v = ((const f16x8*)rp)[i];
#pragma unroll
      for (int c = 0; c < 8; ++c) s += __expf((float)v[c] - mx);
    }
    s += __shfl_xor(s, 1);
    if ((t & 1) == 0) rowc[t >> 1] = -mx * 1.44269504f - __log2f(s);
  }
  __syncthreads();
  float ca[4];
#pragma unroll
  for (int i = 0; i < 4; ++i) ca[i] = rowc[wm + i * 16 + l16];

  // ---- main loop: r8 gemm_nt structure (swizzled) + register transform ----
  const int r0 = t >> 2;
  const int c8 = ((t & 3) ^ ((r0 >> 1) & 3)) * 8;
  const int swz8 = (quad ^ ((l16 >> 1) & 3)) * 8;
  f32x4 acc[4][4] = {};
  for (int k0 = 0; k0 < S_; k0 += 64) {
    __syncthreads();
    stage16(Ab + (long)r0 * S_ + k0 + c8,             As + t * 8);
    stage16(Ab + (long)(r0 + 64) * S_ + k0 + c8,      As + 2048 + t * 8);
    stage16(Ab + (long)r0 * S_ + k0 + 32 + c8,        As + 4096 + t * 8);
    stage16(Ab + (long)(r0 + 64) * S_ + k0 + 32 + c8, As + 6144 + t * 8);
    stage16(Bb + (long)r0 * S_ + k0 + c8,             Bs + t * 8);
    stage16(Bb + (long)(r0 + 64) * S_ + k0 + c8,      Bs + 2048 + t * 8);
    stage16(Bb + (long)r0 * S_ + k0 + 32 + c8,        Bs + 4096 + t * 8);
    stage16(Bb + (long)(r0 + 64) * S_ + k0 + 32 + c8, Bs + 6144 + t * 8);
    __syncthreads();
#pragma unroll
    for (int kk = 0; kk < 2; kk++) {
      f16x8 af[4], bf[4];
#pragma unroll
      for (int i = 0; i < 4; i++) {
        af[i] = *(const f16x8*)&As[kk * 4096 + (wm + i * 16 + l16) * 32 + swz8];
        bf[i] = *(const f16x8*)&Bs[kk * 4096 + (wn + i * 16 + l16) * 32 + swz8];
      }
      // softmax transform: scores -> quantized attn (f16 RNE)
#pragma unroll
      for (int i = 0; i < 4; i++) {
        f16x8 pf;
#pragma unroll
        for (int e = 0; e < 8; e++)
          pf = (e == 0) ? pf : pf;  // keep vector type happy (no-op)
#pragma unroll
        for (int e = 0; e < 8; e++)
          pf[e] = (f16)exp2f(fmaf((float)af[i][e], 1.44269504f, ca[i]));
        af[i] = pf;
      }
#pragma unroll
      for (int i = 0; i < 4; i++)
#pragma unroll
        for (int j = 0; j < 4; j++)
          acc[i][j] = __builtin_amdgcn_mfma_f32_16x16x32_f16(af[i], bf[j], acc[i][j], 0, 0, 0);
    }
  }
  float* Cz = out + (long)blockIdx.z * S_ * H_;
  const long mb = (long)mtile + wm;
  const long nb = (long)ntile + wn;
#pragma unroll
  for (int i = 0; i < 4; i++)
#pragma unroll
    for (int j = 0; j < 4; j++) {
      long m = mb + i * 16 + quad * 4;
      long n = nb + j * 16 + l16;
#pragma unroll
      for (int r = 0; r < 4; r++)
        Cz[(m + r) * H_ + n] = acc[i][j][r];
    }
}

// ---------------------------------------------------------------------------
extern "C" void kernel_launch(void* const* d_in, const int* in_sizes, int n_in,
                              void* d_out, int out_size, void* d_ws, size_t ws_size,
                              hipStream_t stream) {
  (void)in_sizes; (void)n_in; (void)out_size; (void)ws_size;
  const float* x  = (const float*)d_in[0];
  const float* Wq = (const float*)d_in[1];
  const float* bq = (const float*)d_in[2];
  const float* Wk = (const float*)d_in[3];
  const float* bk = (const float*)d_in[4];
  const float* Wv = (const float*)d_in[5];
  const float* bv = (const float*)d_in[6];

  char* ws = (char*)d_ws;
  f16* xh  = (f16*)ws; ws += (size_t)M_ * H_ * 2;          // 16 MiB
  f16* Wh  = (f16*)ws; ws += (size_t)3 * H_ * H_ * 2;      // 6 MiB
  f16* qkv = (f16*)ws; ws += (size_t)2 * M_ * H_ * 2;      // 32 MiB (q, k)
  f16* vT  = (f16*)ws; ws += (size_t)B_ * H_ * S_ * 2;     // 16 MiB
  f16* sc  = (f16*)ws; ws += (size_t)B_ * S_ * S_ * 2;     // 32 MiB (raw quantized scores)

  // 1) x, Wq/Wk/Wv -> fp16 in one launch
  downconvert_all<<<M_ * H_ / 1024 + 3 * H_ * H_ / 1024, 256, 0, stream>>>(
      x, Wq, Wk, Wv, xh, Wh);

  // 2) fused QKV projection + bias + quantize; V written transposed
  qkv_gemm<<<dim3(64, 24), 256, 0, stream>>>(xh, Wh, bq, bk, bv, qkv, vT);

  // 3) scores = quantize(q @ k^T / 32), per batch
  score_gemm<<<dim3(16, 16, 4), 256, 0, stream>>>(
      qkv, qkv + (size_t)M_ * H_, sc, 0.03125f);

  // 4) out = quantize(softmax(scores)) @ vT^T — softmax fused into PV
  pv_gemm<<<dim3(16, 8, 4), 256, 0, stream>>>(sc, vT, (float*)d_out);
}

// Round 10
// 258.442 us; speedup vs baseline: 1.4300x; 1.4300x over previous
//
#include <hip/hip_runtime.h>
#include <hip/hip_fp16.h>

#define B_ 4
#define S_ 2048
#define H_ 1024
#define M_ (B_ * S_)  // 8192 flattened rows of x / q / k / v

typedef _Float16 f16;
typedef _Float16 f16x8 __attribute__((ext_vector_type(8)));
typedef _Float16 f16x4 __attribute__((ext_vector_type(4)));
typedef float f32x4 __attribute__((ext_vector_type(4)));

typedef __attribute__((address_space(3))) unsigned int* lds_u32p;
typedef const __attribute__((address_space(1))) unsigned int* gbl_u32p;

// async global->LDS, 16B per lane; LDS dest is wave-uniform base + lane*16
__device__ __forceinline__ void stage16(const f16* g, f16* l) {
  __builtin_amdgcn_global_load_lds((gbl_u32p)g, (lds_u32p)l, 16, 0, 0);
}

// ---------------------------------------------------------------------------
// One launch: x (8192 blocks) then Wq/Wk/Wv (1024 blocks each) -> fp16 RNE.
__global__ __launch_bounds__(256) void downconvert_all(
    const float* __restrict__ x, const float* __restrict__ W0,
    const float* __restrict__ W1, const float* __restrict__ W2,
    f16* __restrict__ xh, f16* __restrict__ Wh) {
  const int b = blockIdx.x;
  const float* src;
  f16* dst;
  long i;
  if (b < M_ * H_ / 1024) {  // 8192 x-blocks
    src = x; dst = xh;
    i = (long)b * 256 + threadIdx.x;
  } else {
    const int wb = b - M_ * H_ / 1024;
    const int sel = wb >> 10;               // 1024 blocks per W
    src = sel == 0 ? W0 : (sel == 1 ? W1 : W2);
    dst = Wh + (long)sel * H_ * H_;
    i = (long)(wb & 1023) * 256 + threadIdx.x;
  }
  f32x4 v = ((const f32x4*)src)[i];
  f16x4 h;
#pragma unroll
  for (int c = 0; c < 4; c++) h[c] = (f16)v[c];
  ((f16x4*)dst)[i] = h;
}

// ---------------------------------------------------------------------------
// Fused QKV projection — round-0 compute structure VERBATIM, NO swizzle
// (A/B r0/r6/r7/r8: swizzle costs ~8us here; conflicts are hidden).
// r10 change: GRID TRANSPOSED (dim3(24,64), x = sel/ntile, y = mtile).
// Rationale: consecutive 24 blocks now share one 256KB xh A-strip (was:
// 64 blocks sharing a Wh panel while re-reading ALL 16MB of xh per group,
// ~384MB of L3 traffic). With 24 = 3x8, (sel,ntile)->XCD mapping is constant
// across mtile groups, so the 24 Wh panels pin in per-XCD L2 (768KB/XCD);
// A-side L3 traffic drops ~3x and stage latency moves L3->L2.
__global__ __launch_bounds__(256, 2)
void qkv_gemm(const f16* __restrict__ xh, const f16* __restrict__ Wh,
              const float* __restrict__ bq, const float* __restrict__ bk,
              const float* __restrict__ bv, f16* __restrict__ qkv,
              f16* __restrict__ vT) {
  __shared__ __align__(16) f16 As[2 * 128 * 32];  // [chunk0 | chunk1]
  __shared__ __align__(16) f16 Bs[2 * 128 * 32];
  const int t = threadIdx.x;
  const int wave = t >> 6, lane = t & 63;
  const int quad = lane >> 4, l16 = lane & 15;
  const int wm = (wave & 1) * 64, wn = (wave >> 1) * 64;
  const int sel = blockIdx.x >> 3;             // 0=q 1=k 2=v
  const int ntile = (blockIdx.x & 7) * 128;
  const int mtile = blockIdx.y * 128;

  const f16* Ab = xh + (long)mtile * H_;
  const f16* Bb = Wh + (long)sel * H_ * H_ + (long)ntile * H_;

  const int r0 = t >> 2;        // staging row 0..63
  const int c8 = (t & 3) * 8;   // staging col (halfs)

  f32x4 acc[4][4] = {};

  for (int k0 = 0; k0 < H_; k0 += 64) {
    __syncthreads();
    stage16(Ab + (long)r0 * H_ + k0 + c8,             As + t * 8);
    stage16(Ab + (long)(r0 + 64) * H_ + k0 + c8,      As + 2048 + t * 8);
    stage16(Ab + (long)r0 * H_ + k0 + 32 + c8,        As + 4096 + t * 8);
    stage16(Ab + (long)(r0 + 64) * H_ + k0 + 32 + c8, As + 6144 + t * 8);
    stage16(Bb + (long)r0 * H_ + k0 + c8,             Bs + t * 8);
    stage16(Bb + (long)(r0 + 64) * H_ + k0 + c8,      Bs + 2048 + t * 8);
    stage16(Bb + (long)r0 * H_ + k0 + 32 + c8,        Bs + 4096 + t * 8);
    stage16(Bb + (long)(r0 + 64) * H_ + k0 + 32 + c8, Bs + 6144 + t * 8);
    __syncthreads();
#pragma unroll
    for (int kk = 0; kk < 2; kk++) {
      f16x8 ah[4], bh[4];
#pragma unroll
      for (int i = 0; i < 4; i++) {
        ah[i] = *(const f16x8*)&As[kk * 4096 + (wm + i * 16 + l16) * 32 + quad * 8];
        bh[i] = *(const f16x8*)&Bs[kk * 4096 + (wn + i * 16 + l16) * 32 + quad * 8];
      }
#pragma unroll
      for (int i = 0; i < 4; i++)
#pragma unroll
        for (int j = 0; j < 4; j++)
          acc[i][j] = __builtin_amdgcn_mfma_f32_16x16x32_f16(ah[i], bh[j], acc[i][j], 0, 0, 0);
    }
  }

  const float* bias = sel == 0 ? bq : (sel == 1 ? bk : bv);
  if (sel == 2) {
    // V transposed: vT[(b*H + n)*S + t_pos], b = m>>11, t_pos = m&2047.
#pragma unroll
    for (int j = 0; j < 4; j++) {
      int n = ntile + wn + j * 16 + l16;
      float bb = bias[n];
#pragma unroll
      for (int i = 0; i < 4; i++) {
        int m = mtile + wm + i * 16 + quad * 4;
        f16x4 pack;
#pragma unroll
        for (int r = 0; r < 4; r++) pack[r] = (f16)(acc[i][j][r] + bb);
        *(f16x4*)&vT[((long)(m >> 11) * H_ + n) * S_ + (m & 2047)] = pack;
      }
    }
  } else {
    f16* out = qkv + (long)sel * M_ * H_;
#pragma unroll
    for (int j = 0; j < 4; j++) {
      int n = ntile + wn + j * 16 + l16;
      float bb = bias[n];
#pragma unroll
      for (int i = 0; i < 4; i++) {
        int m = mtile + wm + i * 16 + quad * 4;
#pragma unroll
        for (int r = 0; r < 4; r++)
          out[(long)(m + r) * H_ + n] = (f16)(acc[i][j][r] + bb);
      }
    }
  }
}

// ---------------------------------------------------------------------------
// Generic batched NT fp16 GEMM — round-0 structure + chunk-XOR swizzle
// (r8 vs r7 A/B: ~-5us across scores+PV).
// Swizzle: 16B chunk c of row r holds global chunk c ^ ((r>>1)&3); applied
// on the global SOURCE of stage16 (LDS dest linear) and on ds_read address.
// C[z][m][n] = alpha * sum_k A[z][m][k]*B[z][n][k]
template <int OUT_F16>
__global__ __launch_bounds__(256, 2)
void gemm_nt(const f16* __restrict__ A, const f16* __restrict__ Bm,
             void* __restrict__ C, int lda, int ldb, int ldc, int K,
             long sA, long sB, long sC, float alpha) {
  __shared__ __align__(16) f16 As[2 * 128 * 32];
  __shared__ __align__(16) f16 Bs[2 * 128 * 32];
  const int t = threadIdx.x;
  const int wave = t >> 6, lane = t & 63;
  const int quad = lane >> 4, l16 = lane & 15;
  const int wm = (wave & 1) * 64, wn = (wave >> 1) * 64;
  const f16* Ab = A + blockIdx.z * sA + (long)blockIdx.x * 128 * lda;
  const f16* Bb = Bm + blockIdx.z * sB + (long)blockIdx.y * 128 * ldb;
  const int r0 = t >> 2;
  const int c8 = ((t & 3) ^ ((r0 >> 1) & 3)) * 8;    // pre-swizzled source
  const int swz8 = (quad ^ ((l16 >> 1) & 3)) * 8;    // swizzled ds_read
  f32x4 acc[4][4] = {};
  for (int k0 = 0; k0 < K; k0 += 64) {
    __syncthreads();
    stage16(Ab + (long)r0 * lda + k0 + c8,             As + t * 8);
    stage16(Ab + (long)(r0 + 64) * lda + k0 + c8,      As + 2048 + t * 8);
    stage16(Ab + (long)r0 * lda + k0 + 32 + c8,        As + 4096 + t * 8);
    stage16(Ab + (long)(r0 + 64) * lda + k0 + 32 + c8, As + 6144 + t * 8);
    stage16(Bb + (long)r0 * ldb + k0 + c8,             Bs + t * 8);
    stage16(Bb + (long)(r0 + 64) * ldb + k0 + c8,      Bs + 2048 + t * 8);
    stage16(Bb + (long)r0 * ldb + k0 + 32 + c8,        Bs + 4096 + t * 8);
    stage16(Bb + (long)(r0 + 64) * ldb + k0 + 32 + c8, Bs + 6144 + t * 8);
    __syncthreads();
#pragma unroll
    for (int kk = 0; kk < 2; kk++) {
      f16x8 af[4], bf[4];
#pragma unroll
      for (int i = 0; i < 4; i++) {
        af[i] = *(const f16x8*)&As[kk * 4096 + (wm + i * 16 + l16) * 32 + swz8];
        bf[i] = *(const f16x8*)&Bs[kk * 4096 + (wn + i * 16 + l16) * 32 + swz8];
      }
#pragma unroll
      for (int i = 0; i < 4; i++)
#pragma unroll
        for (int j = 0; j < 4; j++)
          acc[i][j] = __builtin_amdgcn_mfma_f32_16x16x32_f16(af[i], bf[j], acc[i][j], 0, 0, 0);
    }
  }
  const long mb = (long)blockIdx.x * 128 + wm;
  const long nb = (long)blockIdx.y * 128 + wn;
#pragma unroll
  for (int i = 0; i < 4; i++)
#pragma unroll
    for (int j = 0; j < 4; j++) {
      long m = mb + i * 16 + quad * 4;
      long n = nb + j * 16 + l16;
#pragma unroll
      for (int r = 0; r < 4; r++) {
        float v = acc[i][j][r] * alpha;
        if (OUT_F16)
          ((f16*)C)[blockIdx.z * sC + (m + r) * ldc + n] = (f16)v;
        else
          ((float*)C)[blockIdx.z * sC + (m + r) * ldc + n] = v;
      }
    }
}

// ---------------------------------------------------------------------------
// Wave-per-row softmax + fp16 quantize: 4 rows per 256-thread block.
// No LDS, no __syncthreads, pure shfl reductions; 64B/lane vectorized I/O.
// (r9 lesson: do NOT fuse the exp into PV — transform must run once per
// element; in PV it is 16x redundant and VALU-bound, 171us vs ~48+15 split.)
__global__ __launch_bounds__(256) void softmax_w(f16* __restrict__ sc) {
  const int wave = threadIdx.x >> 6, lane = threadIdx.x & 63;
  const long row = (long)blockIdx.x * 4 + wave;
  f16* p = sc + row * S_;
  f16x8 v[4];
#pragma unroll
  for (int i = 0; i < 4; ++i) v[i] = ((const f16x8*)p)[i * 64 + lane];
  float f[32];
  float m = -3.0e38f;
#pragma unroll
  for (int i = 0; i < 4; ++i)
#pragma unroll
    for (int c = 0; c < 8; ++c) {
      float x = (float)v[i][c];
      f[i * 8 + c] = x;
      m = fmaxf(m, x);
    }
#pragma unroll
  for (int o = 32; o > 0; o >>= 1) m = fmaxf(m, __shfl_xor(m, o));
  float s = 0.f;
#pragma unroll
  for (int i = 0; i < 32; ++i) { f[i] = __expf(f[i] - m); s += f[i]; }
#pragma unroll
  for (int o = 32; o > 0; o >>= 1) s += __shfl_xor(s, o);
  const float inv = 1.0f / s;
#pragma unroll
  for (int i = 0; i < 4; ++i) {
    f16x8 ov;
#pragma unroll
    for (int c = 0; c < 8; ++c) ov[c] = (f16)(f[i * 8 + c] * inv);
    ((f16x8*)p)[i * 64 + lane] = ov;
  }
}

// ---------------------------------------------------------------------------
extern "C" void kernel_launch(void* const* d_in, const int* in_sizes, int n_in,
                              void* d_out, int out_size, void* d_ws, size_t ws_size,
                              hipStream_t stream) {
  (void)in_sizes; (void)n_in; (void)out_size; (void)ws_size;
  const float* x  = (const float*)d_in[0];
  const float* Wq = (const float*)d_in[1];
  const float* bq = (const float*)d_in[2];
  const float* Wk = (const float*)d_in[3];
  const float* bk = (const float*)d_in[4];
  const float* Wv = (const float*)d_in[5];
  const float* bv = (const float*)d_in[6];

  char* ws = (char*)d_ws;
  f16* xh  = (f16*)ws; ws += (size_t)M_ * H_ * 2;          // 16 MiB
  f16* Wh  = (f16*)ws; ws += (size_t)3 * H_ * H_ * 2;      // 6 MiB
  f16* qkv = (f16*)ws; ws += (size_t)2 * M_ * H_ * 2;      // 32 MiB (q, k)
  f16* vT  = (f16*)ws; ws += (size_t)B_ * H_ * S_ * 2;     // 16 MiB
  f16* sc  = (f16*)ws; ws += (size_t)B_ * S_ * S_ * 2;     // 32 MiB (scores, then attn in-place)

  // 1) x, Wq/Wk/Wv -> fp16 in one launch
  downconvert_all<<<M_ * H_ / 1024 + 3 * H_ * H_ / 1024, 256, 0, stream>>>(
      x, Wq, Wk, Wv, xh, Wh);

  // 2) fused QKV projection + bias + quantize; V written transposed.
  //    TRANSPOSED grid: x = (sel,ntile) [24], y = mtile [64].
  qkv_gemm<<<dim3(24, 64), 256, 0, stream>>>(xh, Wh, bq, bk, bv, qkv, vT);

  // 3) scores = quantize(q @ k^T / 32), per batch — swizzled gemm_nt
  gemm_nt<1><<<dim3(16, 16, 4), 256, 0, stream>>>(
      qkv, qkv + (size_t)M_ * H_, sc, H_, H_, S_, H_,
      (long)S_ * H_, (long)S_ * H_, (long)S_ * S_, 0.03125f);

  // 4) attn = quantize(softmax(scores)) in-place — wave-per-row
  softmax_w<<<M_ / 4, 256, 0, stream>>>(sc);

  // 5) out = attn @ vT^T (fp32 straight to d_out) — swizzled gemm_nt
  gemm_nt<0><<<dim3(16, 8, 4), 256, 0, stream>>>(
      sc, vT, d_out, S_, S_, H_, S_,
      (long)S_ * S_, (long)H_ * S_, (long)S_ * H_, 1.0f);
}